// Round 4
// baseline (217.839 us; speedup 1.0000x reference)
//
#include <hip/hip_runtime.h>

#define N_NODES 10000
#define D 128
#define N_EDGES 640000
#define NB 128                 // persistent blocks
#define EPB (N_EDGES / NB)     // 5000 edges per block
#define NSB 10                 // scan blocks (bid < NSB), 1024 nodes each
#define MAGIC1 0x1F2E3D4Cu
#define MAGIC2 0x5A6B7C8Du

typedef __attribute__((ext_vector_type(8))) short bf16x8;          // MFMA A/B frag
typedef __attribute__((ext_vector_type(4))) float f32x4;           // MFMA acc
typedef __attribute__((ext_vector_type(8))) unsigned short us8;    // 16B bf16 row chunk
typedef __attribute__((ext_vector_type(8))) float f32x8;

// ---------------- fp32 -> bf16 (round-to-nearest-even) ----------------

__device__ __forceinline__ unsigned short f2bf(float f) {
    union { float f; unsigned int i; } v;
    v.f = f;
    unsigned int b = v.i;
    unsigned int rounded = b + 0x7fffu + ((b >> 16) & 1u);
    return (unsigned short)(rounded >> 16);
}

__device__ __forceinline__ float bf2f(unsigned short u) {
    union { unsigned int i; float f; } v;
    v.i = ((unsigned int)u) << 16;
    return v.f;
}

__device__ __forceinline__ f32x8 bf2f8(us8 v) {
    f32x8 r;
#pragma unroll
    for (int t = 0; t < 8; ++t) r[t] = bf2f(v[t]);
    return r;
}

// ---------------- K1: persistent build = cast + hist + colscan/scan + scatter -----
// 128 blocks x 1024 threads: all co-resident (1 block/CU max on 256 CUs, 44KB LDS).
// Inter-block sync: MAGIC-slot arrays (poison-safe, no zero-init) + agent fences.

__global__ __launch_bounds__(1024) void build_kernel(const int* __restrict__ ei,
                                                     const float4* __restrict__ x4,
                                                     const float4* __restrict__ Wl4,
                                                     const float4* __restrict__ Wr4,
                                                     ushort4* __restrict__ xh4,
                                                     ushort4* __restrict__ Wlb4,
                                                     ushort4* __restrict__ Wrb4,
                                                     unsigned short* __restrict__ lrank,
                                                     unsigned short* __restrict__ cnt,
                                                     int* __restrict__ row_start,
                                                     unsigned long long* __restrict__ flags,
                                                     unsigned int* __restrict__ arr1,
                                                     unsigned int* __restrict__ arr2,
                                                     unsigned short* __restrict__ csr) {
    __shared__ int h[N_NODES];
    __shared__ int sc[1024];
    __shared__ int blk_excl_sh;
    const int tid = threadIdx.x;
    const int bid = blockIdx.x;

    for (int n = tid; n < N_NODES; n += 1024) h[n] = 0;
    if (bid < NSB && tid == 0) flags[bid] = 0ULL;    // pre-arrival zero of lookback slots

    // cast x (320000 float4 groups) + W (4096 float4 groups) across the whole grid
    const int gid = bid * 1024 + tid;                // 131072 threads
    for (int i = gid; i < N_NODES * D / 4; i += NB * 1024) {
        float4 v = x4[i];
        ushort4 o;
        o.x = f2bf(v.x); o.y = f2bf(v.y); o.z = f2bf(v.z); o.w = f2bf(v.w);
        xh4[i] = o;
    }
    if (gid < D * D / 4) {
        float4 a = Wl4[gid], b = Wr4[gid];
        ushort4 oa, ob;
        oa.x = f2bf(a.x); oa.y = f2bf(a.y); oa.z = f2bf(a.z); oa.w = f2bf(a.w);
        ob.x = f2bf(b.x); ob.y = f2bf(b.y); ob.z = f2bf(b.z); ob.w = f2bf(b.w);
        Wlb4[gid] = oa;
        Wrb4[gid] = ob;
    }
    __syncthreads();

    // ---- hist: local ranks into lrank, per-block counts into cnt (block-major) ----
    const int base = bid * EPB;
    for (int e = base + tid; e < base + EPB; e += 1024) {
        int d = ei[N_EDGES + e];                     // row 1 = dst
        lrank[e] = (unsigned short)atomicAdd(&h[d], 1);
    }
    __syncthreads();
    for (int n = tid; n < N_NODES; n += 1024)
        cnt[(size_t)bid * N_NODES + n] = (unsigned short)h[n];

    // ---- arrival 1: all 128 histograms visible ----
    __syncthreads();                                 // drains all block stores (vmcnt 0)
    if (tid == 0) {
        __threadfence();                             // agent release: L2 writeback
        __hip_atomic_store(&arr1[bid], MAGIC1, __ATOMIC_RELEASE, __HIP_MEMORY_SCOPE_AGENT);
        int ready;
        do {
            ready = 1;
            for (int j = 0; j < NB; ++j)
                ready &= (__hip_atomic_load(&arr1[j], __ATOMIC_RELAXED,
                                            __HIP_MEMORY_SCOPE_AGENT) == MAGIC1);
            if (!ready) __builtin_amdgcn_s_sleep(8);
        } while (!ready);
    }
    __syncthreads();
    __threadfence();                                 // agent acquire: invalidate stale

    // ---- colscan + node scan + lookback: blocks 0..NSB-1, 1024 nodes each ----
    if (bid < NSB) {
        const int n = bid * 1024 + tid;
        int deg = 0;
        if (n < N_NODES) {
            int s = 0;
#pragma unroll 8
            for (int j = 0; j < NB; ++j) {
                int idx = j * N_NODES + n;           // lane-coalesced column pass
                int v = cnt[idx];
                cnt[idx] = (unsigned short)s;
                s += v;
            }
            deg = s;
        }
        sc[tid] = deg;
        __syncthreads();
        for (int off = 1; off < 1024; off <<= 1) {
            int v = (tid >= off) ? sc[tid - off] : 0;
            __syncthreads();
            sc[tid] += v;
            __syncthreads();
        }
        const int total = sc[1023];
        const int local_excl = sc[tid] - deg;

        if (tid == 0) {
            int excl = 0;
            if (bid == 0) {
                __hip_atomic_store(&flags[0], (2ULL << 32) | (unsigned)total,
                                   __ATOMIC_RELEASE, __HIP_MEMORY_SCOPE_AGENT);
            } else {
                __hip_atomic_store(&flags[bid], (1ULL << 32) | (unsigned)total,
                                   __ATOMIC_RELEASE, __HIP_MEMORY_SCOPE_AGENT);
                int j = bid - 1;
                while (j >= 0) {
                    unsigned long long f = __hip_atomic_load(&flags[j], __ATOMIC_ACQUIRE,
                                                             __HIP_MEMORY_SCOPE_AGENT);
                    unsigned st = (unsigned)(f >> 32);
                    if (st == 0) continue;
                    excl += (int)(unsigned)(f & 0xffffffffULL);
                    if (st == 2) break;
                    --j;
                }
                __hip_atomic_store(&flags[bid], (2ULL << 32) | (unsigned)(excl + total),
                                   __ATOMIC_RELEASE, __HIP_MEMORY_SCOPE_AGENT);
            }
            blk_excl_sh = excl;
        }
        __syncthreads();
        if (n < N_NODES) row_start[n] = blk_excl_sh + local_excl;
        if (bid == NSB - 1 && tid == 0) row_start[N_NODES] = N_EDGES;

        // ---- arrival 2 (scan blocks publish) ----
        __syncthreads();
        if (tid == 0) {
            __threadfence();
            __hip_atomic_store(&arr2[bid], MAGIC2, __ATOMIC_RELEASE, __HIP_MEMORY_SCOPE_AGENT);
        }
    }

    // ---- all blocks wait for row_start + rewritten cnt ----
    if (tid == 0) {
        int ready;
        do {
            ready = 1;
            for (int j = 0; j < NSB; ++j)
                ready &= (__hip_atomic_load(&arr2[j], __ATOMIC_RELAXED,
                                            __HIP_MEMORY_SCOPE_AGENT) == MAGIC2);
            if (!ready) __builtin_amdgcn_s_sleep(8);
        } while (!ready);
    }
    __syncthreads();
    __threadfence();

    // ---- scatter own 5000 edges ----
    for (int e = base + tid; e < base + EPB; e += 1024) {
        int s = ei[e];
        int d = ei[N_EDGES + e];
        int pos = row_start[d] + (int)cnt[(size_t)bid * N_NODES + d] + (int)lrank[e];
        csr[pos] = (unsigned short)s;
    }
}

// ---------------- K2: mean aggregation (verified baseline, unchanged) -------------
// block = 128 threads: lane16 = feature octet (16 x 8 = 128 features), slot = 0..7.

__global__ __launch_bounds__(128) void aggregate_kernel(const us8* __restrict__ xh8,
                                                        const int* __restrict__ row_start,
                                                        const unsigned short* __restrict__ csr,
                                                        us8* __restrict__ aggb8) {
    __shared__ unsigned short idxs[256];
    __shared__ f32x8 red[8][16];
    const int node = blockIdx.x;
    const int lane16 = threadIdx.x & 15;   // feature octet
    const int slot = threadIdx.x >> 4;     // edge slot 0..7
    const int start = row_start[node];
    const int end = row_start[node + 1];

    f32x8 a0 = 0.f, a1 = 0.f, a2 = 0.f, a3 = 0.f;
    for (int cs = start; cs < end; cs += 256) {
        int m = min(256, end - cs);
        if ((int)threadIdx.x < m) idxs[threadIdx.x] = csr[cs + threadIdx.x];
        if ((int)threadIdx.x + 128 < m) idxs[threadIdx.x + 128] = csr[cs + threadIdx.x + 128];
        __syncthreads();
        int j = slot;
        for (; j + 24 < m; j += 32) {
            int s0 = idxs[j], s1 = idxs[j + 8], s2 = idxs[j + 16], s3 = idxs[j + 24];
            us8 v0 = xh8[s0 * 16 + lane16];
            us8 v1 = xh8[s1 * 16 + lane16];
            us8 v2 = xh8[s2 * 16 + lane16];
            us8 v3 = xh8[s3 * 16 + lane16];
            a0 += bf2f8(v0); a1 += bf2f8(v1); a2 += bf2f8(v2); a3 += bf2f8(v3);
        }
        for (; j < m; j += 8) {
            us8 v = xh8[(int)idxs[j] * 16 + lane16];
            a0 += bf2f8(v);
        }
        __syncthreads();
    }
    a0 = (a0 + a1) + (a2 + a3);
    red[slot][lane16] = a0;
    __syncthreads();
    if (slot == 0) {
        f32x8 o = red[0][lane16];
#pragma unroll
        for (int s = 1; s < 8; ++s) o += red[s][lane16];
        int cntE = end - start;
        float inv = (cntE > 0) ? 1.0f / (float)cntE : 0.0f;
        us8 pack;
#pragma unroll
        for (int t = 0; t < 8; ++t) pack[t] = f2bf(o[t] * inv);
        aggb8[node * 16 + lane16] = pack;
    }
}

// ---------------- K3: SAGE linear + residual via bf16 MFMA (verified baseline) ----
// One wave per 16x16 C tile; K=256 as 8 chained mfma_f32_16x16x32_bf16.

__global__ __launch_bounds__(256) void lin_mfma_kernel(const float* __restrict__ x,
                                                       const unsigned short* __restrict__ aggb,
                                                       const unsigned short* __restrict__ xh,
                                                       const unsigned short* __restrict__ Wlb,
                                                       const unsigned short* __restrict__ Wrb,
                                                       const float* __restrict__ bl,
                                                       float* __restrict__ out) {
    const int wave = threadIdx.x >> 6;
    const int lane = threadIdx.x & 63;
    const int l15 = lane & 15;
    const int quad = lane >> 4;
    const int mt = blockIdx.x * 4 + wave;            // M-tile 0..624 (10000 = 625*16)
    if (mt >= 625) return;
    const int row0 = mt * 16;
    const int out0 = blockIdx.y * 16;

    const int m = row0 + l15;
    const int f = out0 + l15;

    const bf16x8* arow = (const bf16x8*)(aggb + (size_t)m * D) + quad;
    const bf16x8* xrow = (const bf16x8*)(xh   + (size_t)m * D) + quad;
    const bf16x8* wlro = (const bf16x8*)(Wlb + (size_t)f * D) + quad;
    const bf16x8* wrro = (const bf16x8*)(Wrb + (size_t)f * D) + quad;

    f32x4 c = {0.f, 0.f, 0.f, 0.f};
#pragma unroll
    for (int kk = 0; kk < 4; ++kk) {
        c = __builtin_amdgcn_mfma_f32_16x16x32_bf16(arow[kk * 4], wlro[kk * 4], c, 0, 0, 0);
        c = __builtin_amdgcn_mfma_f32_16x16x32_bf16(xrow[kk * 4], wrro[kk * 4], c, 0, 0, 0);
    }

    const float bias = bl[f];
#pragma unroll
    for (int r = 0; r < 4; ++r) {
        int row = row0 + quad * 4 + r;
        int idx = row * D + f;
        out[idx] = x[idx] + bias + c[r];
    }
}

extern "C" void kernel_launch(void* const* d_in, const int* in_sizes, int n_in,
                              void* d_out, int out_size, void* d_ws, size_t ws_size,
                              hipStream_t stream) {
    const float* x  = (const float*)d_in[0];
    const int*   ei = (const int*)d_in[1];     // [2, E] int32
    const float* Wl = (const float*)d_in[2];
    const float* bl = (const float*)d_in[3];
    const float* Wr = (const float*)d_in[4];
    float* out = (float*)d_out;

    // workspace layout (16B-aligned segments)
    unsigned long long* flags = (unsigned long long*)d_ws;               // 16 ULL (128 B)
    unsigned int* arr1 = (unsigned int*)(flags + 16);                    // 128 uint (512 B)
    unsigned int* arr2 = arr1 + NB;                                      // 16 uint (64 B)
    int* row_start = (int*)(arr2 + 16);                                  // 10016 ints
    unsigned short* cnt   = (unsigned short*)(row_start + 10016);        // NB*N_NODES us (block-major)
    unsigned short* lrank = cnt + (size_t)NB * N_NODES;                  // N_EDGES us
    unsigned short* csr   = lrank + N_EDGES;                             // N_EDGES us
    unsigned short* xh    = csr + N_EDGES;                               // N_NODES*D (bf16)
    unsigned short* aggb  = xh + (size_t)N_NODES * D;                    // N_NODES*D (bf16)
    unsigned short* Wlb   = aggb + (size_t)N_NODES * D;                  // D*D (bf16)
    unsigned short* Wrb   = Wlb + D * D;                                 // D*D (bf16)

    build_kernel<<<NB, 1024, 0, stream>>>(ei, (const float4*)x, (const float4*)Wl,
                                          (const float4*)Wr, (ushort4*)xh,
                                          (ushort4*)Wlb, (ushort4*)Wrb,
                                          lrank, cnt, row_start, flags, arr1, arr2, csr);
    aggregate_kernel<<<N_NODES, 128, 0, stream>>>((const us8*)xh, row_start, csr,
                                                  (us8*)aggb);
    lin_mfma_kernel<<<dim3(157, 8), 256, 0, stream>>>(x, aggb, xh, Wlb, Wrb, bl, out);
}

// Round 5
// 136.453 us; speedup vs baseline: 1.5964x; 1.5964x over previous
//
#include <hip/hip_runtime.h>

#define N_NODES 10000
#define D 128
#define N_EDGES 640000
#define NB 128                 // histogram blocks
#define EPB (N_EDGES / NB)     // 5000 edges per block
#define SB 40                  // scan blocks
#define NPSB 250               // nodes per scan block
#define NTILES 625             // 10000 / 16 M-tiles

typedef __attribute__((ext_vector_type(8))) short bf16x8;          // MFMA A/B frag
typedef __attribute__((ext_vector_type(4))) float f32x4;           // MFMA acc
typedef __attribute__((ext_vector_type(8))) unsigned short us8;    // 16B bf16 row chunk
typedef __attribute__((ext_vector_type(8))) float f32x8;

// ---------------- fp32 -> bf16 (round-to-nearest-even) ----------------

__device__ __forceinline__ unsigned short f2bf(float f) {
    union { float f; unsigned int i; } v;
    v.f = f;
    unsigned int b = v.i;
    unsigned int rounded = b + 0x7fffu + ((b >> 16) & 1u);
    return (unsigned short)(rounded >> 16);
}

__device__ __forceinline__ float bf2f(unsigned short u) {
    union { unsigned int i; float f; } v;
    v.i = ((unsigned int)u) << 16;
    return v.f;
}

__device__ __forceinline__ f32x8 bf2f8(us8 v) {
    f32x8 r;
#pragma unroll
    for (int t = 0; t < 8; ++t) r[t] = bf2f(v[t]);
    return r;
}

// ---------------- K1: fused cast + LDS histogram (verified 122us baseline) --------

__global__ __launch_bounds__(1024) void hist_cast_kernel(const int* __restrict__ ei,
                                                         const float4* __restrict__ x4,
                                                         const float4* __restrict__ Wl4,
                                                         const float4* __restrict__ Wr4,
                                                         ushort4* __restrict__ xh4,
                                                         ushort4* __restrict__ Wlb4,
                                                         ushort4* __restrict__ Wrb4,
                                                         unsigned short* __restrict__ lrank,
                                                         unsigned short* __restrict__ cnt,
                                                         unsigned long long* __restrict__ flags) {
    __shared__ int h[N_NODES];
    for (int n = threadIdx.x; n < N_NODES; n += 1024) h[n] = 0;
    if (blockIdx.x == 0 && threadIdx.x < SB) flags[threadIdx.x] = 0ULL;

    // cast x (320000 float4 groups) + W (4096 float4 groups) across the whole grid
    const int gid = blockIdx.x * 1024 + threadIdx.x;      // 131072 threads
    for (int i = gid; i < N_NODES * D / 4; i += NB * 1024) {
        float4 v = x4[i];
        ushort4 o;
        o.x = f2bf(v.x); o.y = f2bf(v.y); o.z = f2bf(v.z); o.w = f2bf(v.w);
        xh4[i] = o;
    }
    if (gid < D * D / 4) {
        float4 a = Wl4[gid], b = Wr4[gid];
        ushort4 oa, ob;
        oa.x = f2bf(a.x); oa.y = f2bf(a.y); oa.z = f2bf(a.z); oa.w = f2bf(a.w);
        ob.x = f2bf(b.x); ob.y = f2bf(b.y); ob.z = f2bf(b.z); ob.w = f2bf(b.w);
        Wlb4[gid] = oa;
        Wrb4[gid] = ob;
    }
    __syncthreads();

    const int base = blockIdx.x * EPB;
    for (int e = base + threadIdx.x; e < base + EPB; e += 1024) {
        int d = ei[N_EDGES + e];            // row 1 = dst
        lrank[e] = (unsigned short)atomicAdd(&h[d], 1);
    }
    __syncthreads();
    unsigned short* c = cnt + (size_t)blockIdx.x * N_NODES;
    for (int n = threadIdx.x; n < N_NODES; n += 1024) c[n] = (unsigned short)h[n];
}

// ---------------- K2: fused column scan + node scan (verified 122us baseline) -----

__global__ __launch_bounds__(256) void colscan_scan_kernel(unsigned short* __restrict__ cnt,
                                                           int* __restrict__ row_start,
                                                           unsigned long long* __restrict__ flags) {
    const int t = threadIdx.x;
    const int b = blockIdx.x;
    const int n = b * NPSB + t;            // valid for t < NPSB
    __shared__ int sc[256];
    __shared__ int blk_excl_sh;

    int deg = 0;
    if (t < NPSB) {
        int s = 0;
#pragma unroll 8
        for (int j = 0; j < NB; ++j) {
            int idx = j * N_NODES + n;
            int v = cnt[idx];
            cnt[idx] = (unsigned short)s;
            s += v;
        }
        deg = s;
    }
    sc[t] = deg;
    __syncthreads();
    for (int off = 1; off < 256; off <<= 1) {
        int v = (t >= off) ? sc[t - off] : 0;
        __syncthreads();
        sc[t] += v;
        __syncthreads();
    }
    const int total = sc[255];
    const int local_excl = sc[t] - deg;

    if (t == 0) {
        int excl = 0;
        if (b == 0) {
            __hip_atomic_store(&flags[0], (2ULL << 32) | (unsigned)total,
                               __ATOMIC_RELEASE, __HIP_MEMORY_SCOPE_AGENT);
        } else {
            __hip_atomic_store(&flags[b], (1ULL << 32) | (unsigned)total,
                               __ATOMIC_RELEASE, __HIP_MEMORY_SCOPE_AGENT);
            int j = b - 1;
            while (j >= 0) {
                unsigned long long f = __hip_atomic_load(&flags[j], __ATOMIC_ACQUIRE,
                                                         __HIP_MEMORY_SCOPE_AGENT);
                unsigned st = (unsigned)(f >> 32);
                if (st == 0) continue;
                excl += (int)(unsigned)(f & 0xffffffffULL);
                if (st == 2) break;
                --j;
            }
            __hip_atomic_store(&flags[b], (2ULL << 32) | (unsigned)(excl + total),
                               __ATOMIC_RELEASE, __HIP_MEMORY_SCOPE_AGENT);
        }
        blk_excl_sh = excl;
    }
    __syncthreads();
    if (t < NPSB) row_start[n] = blk_excl_sh + local_excl;
    if (b == SB - 1 && t == 0) row_start[N_NODES] = N_EDGES;
}

// ---------------- K3: scatter (verified 122us baseline) ----------------

__global__ __launch_bounds__(256) void scatter_kernel(const int* __restrict__ ei,
                                                      const int* __restrict__ row_start,
                                                      const unsigned short* __restrict__ cnt,
                                                      const unsigned short* __restrict__ lrank,
                                                      unsigned short* __restrict__ csr) {
    int i = blockIdx.x * 256 + threadIdx.x;
    if (i < N_EDGES) {
        int b = i / EPB;
        int s = ei[i];
        int d = ei[N_EDGES + i];
        int pos = row_start[d] + (int)cnt[b * N_NODES + d] + (int)lrank[i];
        csr[pos] = (unsigned short)s;
    }
}

// ---------------- K4: fused mean-aggregation + SAGE linear + residual -------------
// One block per 16-node M-tile (625 blocks x 256 threads). Aggregate the tile's
// 16 nodes into an LDS bf16 tile, then 4 waves run the 16x128 MFMA directly.

__global__ __launch_bounds__(256) void agg_lin_kernel(const us8* __restrict__ xh8,
                                                      const int* __restrict__ row_start,
                                                      const unsigned short* __restrict__ csr,
                                                      const float* __restrict__ x,
                                                      const unsigned short* __restrict__ xh,
                                                      const unsigned short* __restrict__ Wlb,
                                                      const unsigned short* __restrict__ Wrb,
                                                      const float* __restrict__ bl,
                                                      float* __restrict__ out) {
    __shared__ unsigned short idxs[256];
    __shared__ f32x8 red[16][16];
    __shared__ unsigned short aggT[16][136];   // row stride 272B (16B-aligned)
    const int tid = threadIdx.x;
    const int lane16 = tid & 15;               // feature octet
    const int slot = tid >> 4;                 // edge slot 0..15
    const int wave = tid >> 6;                 // 0..3
    const int lane = tid & 63;
    const int quad = lane >> 4;
    const int l15 = lane & 15;
    const int row0 = blockIdx.x * 16;

    // --- aggregate the tile's 16 nodes, one at a time, whole block per node ---
    for (int nn = 0; nn < 16; ++nn) {
        const int node = row0 + nn;
        const int start = row_start[node];
        const int end = row_start[node + 1];
        f32x8 a0 = 0.f, a1 = 0.f, a2 = 0.f, a3 = 0.f;
        for (int cs = start; cs < end; cs += 256) {
            int m = min(256, end - cs);
            __syncthreads();                   // idxs reuse guard (also guards red/aggT)
            if (tid < m) idxs[tid] = csr[cs + tid];
            __syncthreads();
            int j = slot;
            for (; j + 48 < m; j += 64) {
                int s0 = idxs[j], s1 = idxs[j + 16], s2 = idxs[j + 32], s3 = idxs[j + 48];
                a0 += bf2f8(xh8[s0 * 16 + lane16]);
                a1 += bf2f8(xh8[s1 * 16 + lane16]);
                a2 += bf2f8(xh8[s2 * 16 + lane16]);
                a3 += bf2f8(xh8[s3 * 16 + lane16]);
            }
            for (; j < m; j += 16) a0 += bf2f8(xh8[(int)idxs[j] * 16 + lane16]);
        }
        a0 = (a0 + a1) + (a2 + a3);
        __syncthreads();                       // red free (prev node's reads done)
        red[slot][lane16] = a0;
        __syncthreads();
        if (slot == 0) {                       // 16 threads reduce 16 slots
            f32x8 o = red[0][lane16];
#pragma unroll
            for (int s2 = 1; s2 < 16; ++s2) o += red[s2][lane16];
            int cE = end - start;
            float inv = (cE > 0) ? 1.0f / (float)cE : 0.0f;
            us8 pack;
#pragma unroll
            for (int t2 = 0; t2 < 8; ++t2) pack[t2] = f2bf(o[t2] * inv);
            *(us8*)&aggT[nn][lane16 * 8] = pack;
        }
    }
    __syncthreads();                           // aggT complete

    // --- MFMA: wave w computes output col-tiles {2w, 2w+1} for this 16-row block ---
    const unsigned short* ap = &aggT[l15][quad * 8];
    const bf16x8* xrow = (const bf16x8*)(xh + (size_t)(row0 + l15) * D) + quad;
    const int f0 = wave * 32 + l15;
    const int f1 = f0 + 16;
    const bf16x8* wl0 = (const bf16x8*)(Wlb + (size_t)f0 * D) + quad;
    const bf16x8* wr0 = (const bf16x8*)(Wrb + (size_t)f0 * D) + quad;
    const bf16x8* wl1 = (const bf16x8*)(Wlb + (size_t)f1 * D) + quad;
    const bf16x8* wr1 = (const bf16x8*)(Wrb + (size_t)f1 * D) + quad;
    f32x4 c0 = {0.f, 0.f, 0.f, 0.f};
    f32x4 c1 = {0.f, 0.f, 0.f, 0.f};
#pragma unroll
    for (int kk = 0; kk < 4; ++kk) {
        bf16x8 af = *(const bf16x8*)(ap + kk * 32);
        bf16x8 xf = xrow[kk * 4];
        c0 = __builtin_amdgcn_mfma_f32_16x16x32_bf16(af, wl0[kk * 4], c0, 0, 0, 0);
        c0 = __builtin_amdgcn_mfma_f32_16x16x32_bf16(xf, wr0[kk * 4], c0, 0, 0, 0);
        c1 = __builtin_amdgcn_mfma_f32_16x16x32_bf16(af, wl1[kk * 4], c1, 0, 0, 0);
        c1 = __builtin_amdgcn_mfma_f32_16x16x32_bf16(xf, wr1[kk * 4], c1, 0, 0, 0);
    }
    const float b0 = bl[f0];
    const float b1 = bl[f1];
#pragma unroll
    for (int r = 0; r < 4; ++r) {
        int row = row0 + quad * 4 + r;
        int i0 = row * D + f0;
        int i1 = row * D + f1;
        out[i0] = x[i0] + b0 + c0[r];
        out[i1] = x[i1] + b1 + c1[r];
    }
}

extern "C" void kernel_launch(void* const* d_in, const int* in_sizes, int n_in,
                              void* d_out, int out_size, void* d_ws, size_t ws_size,
                              hipStream_t stream) {
    const float* x  = (const float*)d_in[0];
    const int*   ei = (const int*)d_in[1];     // [2, E] int32
    const float* Wl = (const float*)d_in[2];
    const float* bl = (const float*)d_in[3];
    const float* Wr = (const float*)d_in[4];
    float* out = (float*)d_out;

    // workspace layout (16B-aligned segments)
    unsigned long long* flags = (unsigned long long*)d_ws;               // 64 ULL
    int* row_start = (int*)(flags + 64);                                 // 10016 ints
    unsigned short* cnt   = (unsigned short*)(row_start + 10016);        // NB*N_NODES us
    unsigned short* lrank = cnt + (size_t)NB * N_NODES;                  // N_EDGES us
    unsigned short* csr   = lrank + N_EDGES;                             // N_EDGES us
    unsigned short* xh    = csr + N_EDGES;                               // N_NODES*D (bf16)
    unsigned short* Wlb   = xh + (size_t)N_NODES * D;                    // D*D (bf16)
    unsigned short* Wrb   = Wlb + D * D;                                 // D*D (bf16)

    hist_cast_kernel<<<NB, 1024, 0, stream>>>(ei, (const float4*)x, (const float4*)Wl,
                                              (const float4*)Wr, (ushort4*)xh,
                                              (ushort4*)Wlb, (ushort4*)Wrb,
                                              lrank, cnt, flags);
    colscan_scan_kernel<<<SB, 256, 0, stream>>>(cnt, row_start, flags);
    scatter_kernel<<<(N_EDGES + 255) / 256, 256, 0, stream>>>(ei, row_start, cnt, lrank, csr);
    agg_lin_kernel<<<NTILES, 256, 0, stream>>>((const us8*)xh, row_start, csr,
                                               x, xh, Wlb, Wrb, bl, out);
}

// Round 6
// 129.323 us; speedup vs baseline: 1.6845x; 1.0551x over previous
//
#include <hip/hip_runtime.h>

#define N_NODES 10000
#define D 128
#define N_EDGES 640000
#define NB 256                 // histogram blocks (one per CU)
#define EPB (N_EDGES / NB)     // 2500 edges per block
#define SB 40                  // scan blocks
#define NPSB 250               // nodes per scan block

typedef __attribute__((ext_vector_type(8))) short bf16x8;          // MFMA A/B frag
typedef __attribute__((ext_vector_type(4))) float f32x4;           // MFMA acc
typedef __attribute__((ext_vector_type(8))) unsigned short us8;    // 16B bf16 row chunk
typedef __attribute__((ext_vector_type(8))) float f32x8;

// ---------------- fp32 -> bf16 (round-to-nearest-even) ----------------

__device__ __forceinline__ unsigned short f2bf(float f) {
    union { float f; unsigned int i; } v;
    v.f = f;
    unsigned int b = v.i;
    unsigned int rounded = b + 0x7fffu + ((b >> 16) & 1u);
    return (unsigned short)(rounded >> 16);
}

__device__ __forceinline__ float bf2f(unsigned short u) {
    union { unsigned int i; float f; } v;
    v.i = ((unsigned int)u) << 16;
    return v.f;
}

__device__ __forceinline__ f32x8 bf2f8(us8 v) {
    f32x8 r;
#pragma unroll
    for (int t = 0; t < 8; ++t) r[t] = bf2f(v[t]);
    return r;
}

// ---------------- K1: fused cast + LDS histogram (now 256 blocks = full GPU) ------

__global__ __launch_bounds__(1024) void hist_cast_kernel(const int* __restrict__ ei,
                                                         const float4* __restrict__ x4,
                                                         const float4* __restrict__ Wl4,
                                                         const float4* __restrict__ Wr4,
                                                         ushort4* __restrict__ xh4,
                                                         ushort4* __restrict__ Wlb4,
                                                         ushort4* __restrict__ Wrb4,
                                                         unsigned short* __restrict__ lrank,
                                                         unsigned short* __restrict__ cnt,
                                                         unsigned long long* __restrict__ flags) {
    __shared__ int h[N_NODES];
    for (int n = threadIdx.x; n < N_NODES; n += 1024) h[n] = 0;
    if (blockIdx.x == 0 && threadIdx.x < SB) flags[threadIdx.x] = 0ULL;

    // cast x (320000 float4 groups) + W (4096 float4 groups) across the whole grid
    const int gid = blockIdx.x * 1024 + threadIdx.x;      // 262144 threads
    for (int i = gid; i < N_NODES * D / 4; i += NB * 1024) {
        float4 v = x4[i];
        ushort4 o;
        o.x = f2bf(v.x); o.y = f2bf(v.y); o.z = f2bf(v.z); o.w = f2bf(v.w);
        xh4[i] = o;
    }
    if (gid < D * D / 4) {
        float4 a = Wl4[gid], b = Wr4[gid];
        ushort4 oa, ob;
        oa.x = f2bf(a.x); oa.y = f2bf(a.y); oa.z = f2bf(a.z); oa.w = f2bf(a.w);
        ob.x = f2bf(b.x); ob.y = f2bf(b.y); ob.z = f2bf(b.z); ob.w = f2bf(b.w);
        Wlb4[gid] = oa;
        Wrb4[gid] = ob;
    }
    __syncthreads();

    const int base = blockIdx.x * EPB;
    for (int e = base + threadIdx.x; e < base + EPB; e += 1024) {
        int d = ei[N_EDGES + e];            // row 1 = dst
        lrank[e] = (unsigned short)atomicAdd(&h[d], 1);
    }
    __syncthreads();
    unsigned short* c = cnt + (size_t)blockIdx.x * N_NODES;
    for (int n = threadIdx.x; n < N_NODES; n += 1024) c[n] = (unsigned short)h[n];
}

// ---------------- K2: fused column scan + node scan (verified; NB=256 steps) ------

__global__ __launch_bounds__(256) void colscan_scan_kernel(unsigned short* __restrict__ cnt,
                                                           int* __restrict__ row_start,
                                                           unsigned long long* __restrict__ flags) {
    const int t = threadIdx.x;
    const int b = blockIdx.x;
    const int n = b * NPSB + t;            // valid for t < NPSB
    __shared__ int sc[256];
    __shared__ int blk_excl_sh;

    int deg = 0;
    if (t < NPSB) {
        int s = 0;
#pragma unroll 8
        for (int j = 0; j < NB; ++j) {
            int idx = j * N_NODES + n;
            int v = cnt[idx];
            cnt[idx] = (unsigned short)s;
            s += v;
        }
        deg = s;
    }
    sc[t] = deg;
    __syncthreads();
    for (int off = 1; off < 256; off <<= 1) {
        int v = (t >= off) ? sc[t - off] : 0;
        __syncthreads();
        sc[t] += v;
        __syncthreads();
    }
    const int total = sc[255];
    const int local_excl = sc[t] - deg;

    if (t == 0) {
        int excl = 0;
        if (b == 0) {
            __hip_atomic_store(&flags[0], (2ULL << 32) | (unsigned)total,
                               __ATOMIC_RELEASE, __HIP_MEMORY_SCOPE_AGENT);
        } else {
            __hip_atomic_store(&flags[b], (1ULL << 32) | (unsigned)total,
                               __ATOMIC_RELEASE, __HIP_MEMORY_SCOPE_AGENT);
            int j = b - 1;
            while (j >= 0) {
                unsigned long long f = __hip_atomic_load(&flags[j], __ATOMIC_ACQUIRE,
                                                         __HIP_MEMORY_SCOPE_AGENT);
                unsigned st = (unsigned)(f >> 32);
                if (st == 0) continue;
                excl += (int)(unsigned)(f & 0xffffffffULL);
                if (st == 2) break;
                --j;
            }
            __hip_atomic_store(&flags[b], (2ULL << 32) | (unsigned)(excl + total),
                               __ATOMIC_RELEASE, __HIP_MEMORY_SCOPE_AGENT);
        }
        blk_excl_sh = excl;
    }
    __syncthreads();
    if (t < NPSB) row_start[n] = blk_excl_sh + local_excl;
    if (b == SB - 1 && t == 0) row_start[N_NODES] = N_EDGES;
}

// ---------------- K3: scatter (verified baseline; EPB=2500) ----------------

__global__ __launch_bounds__(256) void scatter_kernel(const int* __restrict__ ei,
                                                      const int* __restrict__ row_start,
                                                      const unsigned short* __restrict__ cnt,
                                                      const unsigned short* __restrict__ lrank,
                                                      unsigned short* __restrict__ csr) {
    int i = blockIdx.x * 256 + threadIdx.x;
    if (i < N_EDGES) {
        int b = i / EPB;
        int s = ei[i];
        int d = ei[N_EDGES + i];
        int pos = row_start[d] + (int)cnt[b * N_NODES + d] + (int)lrank[i];
        csr[pos] = (unsigned short)s;
    }
}

// ---------------- K4: mean aggregation, stage-free (direct csr loads) -------------
// block = 128 threads: lane16 = feature octet, slot = 0..7 (each slot strides 8
// edges). No LDS staging of indices -> no per-chunk barriers; 4-deep ILP gather.

__global__ __launch_bounds__(128) void aggregate_kernel(const us8* __restrict__ xh8,
                                                        const int* __restrict__ row_start,
                                                        const unsigned short* __restrict__ csr,
                                                        us8* __restrict__ aggb8) {
    __shared__ f32x8 red[8][16];
    const int node = blockIdx.x;
    const int lane16 = threadIdx.x & 15;   // feature octet
    const int slot = threadIdx.x >> 4;     // edge slot 0..7
    const int start = row_start[node];
    const int end = row_start[node + 1];

    f32x8 a0 = 0.f, a1 = 0.f, a2 = 0.f, a3 = 0.f;
    int j = start + slot;
    for (; j + 24 < end; j += 32) {
        int s0 = csr[j], s1 = csr[j + 8], s2 = csr[j + 16], s3 = csr[j + 24];
        us8 v0 = xh8[s0 * 16 + lane16];
        us8 v1 = xh8[s1 * 16 + lane16];
        us8 v2 = xh8[s2 * 16 + lane16];
        us8 v3 = xh8[s3 * 16 + lane16];
        a0 += bf2f8(v0); a1 += bf2f8(v1); a2 += bf2f8(v2); a3 += bf2f8(v3);
    }
    for (; j < end; j += 8) {
        us8 v = xh8[(int)csr[j] * 16 + lane16];
        a0 += bf2f8(v);
    }
    a0 = (a0 + a1) + (a2 + a3);
    red[slot][lane16] = a0;
    __syncthreads();
    if (slot == 0) {
        f32x8 o = red[0][lane16];
#pragma unroll
        for (int s = 1; s < 8; ++s) o += red[s][lane16];
        int cntE = end - start;
        float inv = (cntE > 0) ? 1.0f / (float)cntE : 0.0f;
        us8 pack;
#pragma unroll
        for (int t = 0; t < 8; ++t) pack[t] = f2bf(o[t] * inv);
        aggb8[node * 16 + lane16] = pack;
    }
}

// ---------------- K5: SAGE linear + residual via bf16 MFMA (verified baseline) ----
// One wave per 16x16 C tile; K=256 as 8 chained mfma_f32_16x16x32_bf16.

__global__ __launch_bounds__(256) void lin_mfma_kernel(const float* __restrict__ x,
                                                       const unsigned short* __restrict__ aggb,
                                                       const unsigned short* __restrict__ xh,
                                                       const unsigned short* __restrict__ Wlb,
                                                       const unsigned short* __restrict__ Wrb,
                                                       const float* __restrict__ bl,
                                                       float* __restrict__ out) {
    const int wave = threadIdx.x >> 6;
    const int lane = threadIdx.x & 63;
    const int l15 = lane & 15;
    const int quad = lane >> 4;
    const int mt = blockIdx.x * 4 + wave;            // M-tile 0..624 (10000 = 625*16)
    if (mt >= 625) return;
    const int row0 = mt * 16;
    const int out0 = blockIdx.y * 16;

    const int m = row0 + l15;
    const int f = out0 + l15;

    const bf16x8* arow = (const bf16x8*)(aggb + (size_t)m * D) + quad;
    const bf16x8* xrow = (const bf16x8*)(xh   + (size_t)m * D) + quad;
    const bf16x8* wlro = (const bf16x8*)(Wlb + (size_t)f * D) + quad;
    const bf16x8* wrro = (const bf16x8*)(Wrb + (size_t)f * D) + quad;

    f32x4 c = {0.f, 0.f, 0.f, 0.f};
#pragma unroll
    for (int kk = 0; kk < 4; ++kk) {
        c = __builtin_amdgcn_mfma_f32_16x16x32_bf16(arow[kk * 4], wlro[kk * 4], c, 0, 0, 0);
        c = __builtin_amdgcn_mfma_f32_16x16x32_bf16(xrow[kk * 4], wrro[kk * 4], c, 0, 0, 0);
    }

    const float bias = bl[f];
#pragma unroll
    for (int r = 0; r < 4; ++r) {
        int row = row0 + quad * 4 + r;
        int idx = row * D + f;
        out[idx] = x[idx] + bias + c[r];
    }
}

extern "C" void kernel_launch(void* const* d_in, const int* in_sizes, int n_in,
                              void* d_out, int out_size, void* d_ws, size_t ws_size,
                              hipStream_t stream) {
    const float* x  = (const float*)d_in[0];
    const int*   ei = (const int*)d_in[1];     // [2, E] int32
    const float* Wl = (const float*)d_in[2];
    const float* bl = (const float*)d_in[3];
    const float* Wr = (const float*)d_in[4];
    float* out = (float*)d_out;

    // workspace layout (16B-aligned segments)
    unsigned long long* flags = (unsigned long long*)d_ws;               // 64 ULL
    int* row_start = (int*)(flags + 64);                                 // 10016 ints
    unsigned short* cnt   = (unsigned short*)(row_start + 10016);        // NB*N_NODES us
    unsigned short* lrank = cnt + (size_t)NB * N_NODES;                  // N_EDGES us
    unsigned short* csr   = lrank + N_EDGES;                             // N_EDGES us
    unsigned short* xh    = csr + N_EDGES;                               // N_NODES*D (bf16)
    unsigned short* aggb  = xh + (size_t)N_NODES * D;                    // N_NODES*D (bf16)
    unsigned short* Wlb   = aggb + (size_t)N_NODES * D;                  // D*D (bf16)
    unsigned short* Wrb   = Wlb + D * D;                                 // D*D (bf16)

    hist_cast_kernel<<<NB, 1024, 0, stream>>>(ei, (const float4*)x, (const float4*)Wl,
                                              (const float4*)Wr, (ushort4*)xh,
                                              (ushort4*)Wlb, (ushort4*)Wrb,
                                              lrank, cnt, flags);
    colscan_scan_kernel<<<SB, 256, 0, stream>>>(cnt, row_start, flags);
    scatter_kernel<<<(N_EDGES + 255) / 256, 256, 0, stream>>>(ei, row_start, cnt, lrank, csr);
    aggregate_kernel<<<N_NODES, 128, 0, stream>>>((const us8*)xh, row_start, csr,
                                                  (us8*)aggb);
    lin_mfma_kernel<<<dim3(157, 8), 256, 0, stream>>>(x, aggb, xh, Wlb, Wrb, bl, out);
}

// Round 7
// 121.467 us; speedup vs baseline: 1.7934x; 1.0647x over previous
//
#include <hip/hip_runtime.h>

#define N_NODES 10000
#define D 128
#define N_EDGES 640000
#define NB 128                 // histogram blocks
#define EPB (N_EDGES / NB)     // 5000 edges per block
#define SB 40                  // scan blocks
#define NPSB 250               // nodes per scan block

typedef __attribute__((ext_vector_type(8))) short bf16x8;          // MFMA A/B frag
typedef __attribute__((ext_vector_type(4))) float f32x4;           // MFMA acc
typedef __attribute__((ext_vector_type(8))) unsigned short us8;    // 16B bf16 row chunk
typedef __attribute__((ext_vector_type(8))) float f32x8;

// ---------------- fp32 -> bf16 (round-to-nearest-even) ----------------

__device__ __forceinline__ unsigned short f2bf(float f) {
    union { float f; unsigned int i; } v;
    v.f = f;
    unsigned int b = v.i;
    unsigned int rounded = b + 0x7fffu + ((b >> 16) & 1u);
    return (unsigned short)(rounded >> 16);
}

__device__ __forceinline__ float bf2f(unsigned short u) {
    union { unsigned int i; float f; } v;
    v.i = ((unsigned int)u) << 16;
    return v.f;
}

__device__ __forceinline__ f32x8 bf2f8(us8 v) {
    f32x8 r;
#pragma unroll
    for (int t = 0; t < 8; ++t) r[t] = bf2f(v[t]);
    return r;
}

// ---------------- K1: fused cast + PACKED LDS histogram ----------------
// Two nodes per int (counts <= 5000 < 2^16, low-field adds never carry).
// Halves LDS zero-init and cnt writeback vs the 122us baseline.

__global__ __launch_bounds__(1024) void hist_cast_kernel(const int* __restrict__ ei,
                                                         const float4* __restrict__ x4,
                                                         const float4* __restrict__ Wl4,
                                                         const float4* __restrict__ Wr4,
                                                         ushort4* __restrict__ xh4,
                                                         ushort4* __restrict__ Wlb4,
                                                         ushort4* __restrict__ Wrb4,
                                                         unsigned short* __restrict__ lrank,
                                                         unsigned short* __restrict__ cnt,
                                                         unsigned long long* __restrict__ flags) {
    __shared__ unsigned int h[N_NODES / 2];          // packed: node n -> word n>>1, half n&1
    for (int w = threadIdx.x; w < N_NODES / 2; w += 1024) h[w] = 0u;
    if (blockIdx.x == 0 && threadIdx.x < SB) flags[threadIdx.x] = 0ULL;

    // cast x (320000 float4 groups) + W (4096 float4 groups) across the whole grid
    const int gid = blockIdx.x * 1024 + threadIdx.x;      // 131072 threads
    for (int i = gid; i < N_NODES * D / 4; i += NB * 1024) {
        float4 v = x4[i];
        ushort4 o;
        o.x = f2bf(v.x); o.y = f2bf(v.y); o.z = f2bf(v.z); o.w = f2bf(v.w);
        xh4[i] = o;
    }
    if (gid < D * D / 4) {
        float4 a = Wl4[gid], b = Wr4[gid];
        ushort4 oa, ob;
        oa.x = f2bf(a.x); oa.y = f2bf(a.y); oa.z = f2bf(a.z); oa.w = f2bf(a.w);
        ob.x = f2bf(b.x); ob.y = f2bf(b.y); ob.z = f2bf(b.z); ob.w = f2bf(b.w);
        Wlb4[gid] = oa;
        Wrb4[gid] = ob;
    }
    __syncthreads();

    const int base = blockIdx.x * EPB;
    for (int e = base + threadIdx.x; e < base + EPB; e += 1024) {
        int d = ei[N_EDGES + e];                     // row 1 = dst
        int sh = (d & 1) << 4;
        unsigned int old = atomicAdd(&h[d >> 1], 1u << sh);
        lrank[e] = (unsigned short)((old >> sh) & 0xffffu);
    }
    __syncthreads();
    // packed writeback: one uint = counts of nodes {2w, 2w+1} (little-endian ushort pair)
    unsigned int* c = (unsigned int*)(cnt + (size_t)blockIdx.x * N_NODES);
    for (int w = threadIdx.x; w < N_NODES / 2; w += 1024) c[w] = h[w];
}

// ---------------- K2: fused column scan + node scan (verified 122us baseline) -----

__global__ __launch_bounds__(256) void colscan_scan_kernel(unsigned short* __restrict__ cnt,
                                                           int* __restrict__ row_start,
                                                           unsigned long long* __restrict__ flags) {
    const int t = threadIdx.x;
    const int b = blockIdx.x;
    const int n = b * NPSB + t;            // valid for t < NPSB
    __shared__ int sc[256];
    __shared__ int blk_excl_sh;

    int deg = 0;
    if (t < NPSB) {
        int s = 0;
#pragma unroll 8
        for (int j = 0; j < NB; ++j) {
            int idx = j * N_NODES + n;
            int v = cnt[idx];
            cnt[idx] = (unsigned short)s;
            s += v;
        }
        deg = s;
    }
    sc[t] = deg;
    __syncthreads();
    for (int off = 1; off < 256; off <<= 1) {
        int v = (t >= off) ? sc[t - off] : 0;
        __syncthreads();
        sc[t] += v;
        __syncthreads();
    }
    const int total = sc[255];
    const int local_excl = sc[t] - deg;

    if (t == 0) {
        int excl = 0;
        if (b == 0) {
            __hip_atomic_store(&flags[0], (2ULL << 32) | (unsigned)total,
                               __ATOMIC_RELEASE, __HIP_MEMORY_SCOPE_AGENT);
        } else {
            __hip_atomic_store(&flags[b], (1ULL << 32) | (unsigned)total,
                               __ATOMIC_RELEASE, __HIP_MEMORY_SCOPE_AGENT);
            int j = b - 1;
            while (j >= 0) {
                unsigned long long f = __hip_atomic_load(&flags[j], __ATOMIC_ACQUIRE,
                                                         __HIP_MEMORY_SCOPE_AGENT);
                unsigned st = (unsigned)(f >> 32);
                if (st == 0) continue;
                excl += (int)(unsigned)(f & 0xffffffffULL);
                if (st == 2) break;
                --j;
            }
            __hip_atomic_store(&flags[b], (2ULL << 32) | (unsigned)(excl + total),
                               __ATOMIC_RELEASE, __HIP_MEMORY_SCOPE_AGENT);
        }
        blk_excl_sh = excl;
    }
    __syncthreads();
    if (t < NPSB) row_start[n] = blk_excl_sh + local_excl;
    if (b == SB - 1 && t == 0) row_start[N_NODES] = N_EDGES;
}

// ---------------- K3: scatter (verified 122us baseline) ----------------

__global__ __launch_bounds__(256) void scatter_kernel(const int* __restrict__ ei,
                                                      const int* __restrict__ row_start,
                                                      const unsigned short* __restrict__ cnt,
                                                      const unsigned short* __restrict__ lrank,
                                                      unsigned short* __restrict__ csr) {
    int i = blockIdx.x * 256 + threadIdx.x;
    if (i < N_EDGES) {
        int b = i / EPB;
        int s = ei[i];
        int d = ei[N_EDGES + i];
        int pos = row_start[d] + (int)cnt[b * N_NODES + d] + (int)lrank[i];
        csr[pos] = (unsigned short)s;
    }
}

// ---------------- K4: mean aggregation, wave-per-node, barrier-free --------------
// 2500 blocks x 256 threads = 10000 waves; wave w handles node blockIdx*4+w.
// 16-lane groups cover 128 features (us8 each); 4 slots x 4-deep ILP; cross-slot
// reduce via 2 shuffle-xor steps. No LDS, no __syncthreads.

__global__ __launch_bounds__(256) void aggregate_kernel(const us8* __restrict__ xh8,
                                                        const int* __restrict__ row_start,
                                                        const unsigned short* __restrict__ csr,
                                                        us8* __restrict__ aggb8) {
    const int node = blockIdx.x * 4 + (threadIdx.x >> 6);
    const int lane = threadIdx.x & 63;
    const int lane16 = lane & 15;          // feature octet
    const int slot = lane >> 4;            // edge slot 0..3
    const int start = row_start[node];
    const int end = row_start[node + 1];

    f32x8 a0 = 0.f, a1 = 0.f, a2 = 0.f, a3 = 0.f;
    int j = start + slot;
    for (; j + 12 < end; j += 16) {
        int s0 = csr[j], s1 = csr[j + 4], s2 = csr[j + 8], s3 = csr[j + 12];
        a0 += bf2f8(xh8[s0 * 16 + lane16]);
        a1 += bf2f8(xh8[s1 * 16 + lane16]);
        a2 += bf2f8(xh8[s2 * 16 + lane16]);
        a3 += bf2f8(xh8[s3 * 16 + lane16]);
    }
    for (; j < end; j += 4) a0 += bf2f8(xh8[(int)csr[j] * 16 + lane16]);
    a0 = (a0 + a1) + (a2 + a3);

#pragma unroll
    for (int t = 0; t < 8; ++t) {          // combine slots: lanes xor 16, then xor 32
        float v = a0[t];
        v += __shfl_xor(v, 16, 64);
        v += __shfl_xor(v, 32, 64);
        a0[t] = v;
    }
    if (slot == 0) {
        int cE = end - start;
        float inv = (cE > 0) ? 1.0f / (float)cE : 0.0f;
        us8 pack;
#pragma unroll
        for (int t = 0; t < 8; ++t) pack[t] = f2bf(a0[t] * inv);
        aggb8[node * 16 + lane16] = pack;
    }
}

// ---------------- K5: SAGE linear + residual via bf16 MFMA (verified baseline) ----
// One wave per 16x16 C tile; K=256 as 8 chained mfma_f32_16x16x32_bf16.

__global__ __launch_bounds__(256) void lin_mfma_kernel(const float* __restrict__ x,
                                                       const unsigned short* __restrict__ aggb,
                                                       const unsigned short* __restrict__ xh,
                                                       const unsigned short* __restrict__ Wlb,
                                                       const unsigned short* __restrict__ Wrb,
                                                       const float* __restrict__ bl,
                                                       float* __restrict__ out) {
    const int wave = threadIdx.x >> 6;
    const int lane = threadIdx.x & 63;
    const int l15 = lane & 15;
    const int quad = lane >> 4;
    const int mt = blockIdx.x * 4 + wave;            // M-tile 0..624 (10000 = 625*16)
    if (mt >= 625) return;
    const int row0 = mt * 16;
    const int out0 = blockIdx.y * 16;

    const int m = row0 + l15;
    const int f = out0 + l15;

    const bf16x8* arow = (const bf16x8*)(aggb + (size_t)m * D) + quad;
    const bf16x8* xrow = (const bf16x8*)(xh   + (size_t)m * D) + quad;
    const bf16x8* wlro = (const bf16x8*)(Wlb + (size_t)f * D) + quad;
    const bf16x8* wrro = (const bf16x8*)(Wrb + (size_t)f * D) + quad;

    f32x4 c = {0.f, 0.f, 0.f, 0.f};
#pragma unroll
    for (int kk = 0; kk < 4; ++kk) {
        c = __builtin_amdgcn_mfma_f32_16x16x32_bf16(arow[kk * 4], wlro[kk * 4], c, 0, 0, 0);
        c = __builtin_amdgcn_mfma_f32_16x16x32_bf16(xrow[kk * 4], wrro[kk * 4], c, 0, 0, 0);
    }

    const float bias = bl[f];
#pragma unroll
    for (int r = 0; r < 4; ++r) {
        int row = row0 + quad * 4 + r;
        int idx = row * D + f;
        out[idx] = x[idx] + bias + c[r];
    }
}

extern "C" void kernel_launch(void* const* d_in, const int* in_sizes, int n_in,
                              void* d_out, int out_size, void* d_ws, size_t ws_size,
                              hipStream_t stream) {
    const float* x  = (const float*)d_in[0];
    const int*   ei = (const int*)d_in[1];     // [2, E] int32
    const float* Wl = (const float*)d_in[2];
    const float* bl = (const float*)d_in[3];
    const float* Wr = (const float*)d_in[4];
    float* out = (float*)d_out;

    // workspace layout (16B-aligned segments)
    unsigned long long* flags = (unsigned long long*)d_ws;               // 64 ULL
    int* row_start = (int*)(flags + 64);                                 // 10016 ints
    unsigned short* cnt   = (unsigned short*)(row_start + 10016);        // NB*N_NODES us
    unsigned short* lrank = cnt + (size_t)NB * N_NODES;                  // N_EDGES us
    unsigned short* csr   = lrank + N_EDGES;                             // N_EDGES us
    unsigned short* xh    = csr + N_EDGES;                               // N_NODES*D (bf16)
    unsigned short* aggb  = xh + (size_t)N_NODES * D;                    // N_NODES*D (bf16)
    unsigned short* Wlb   = aggb + (size_t)N_NODES * D;                  // D*D (bf16)
    unsigned short* Wrb   = Wlb + D * D;                                 // D*D (bf16)

    hist_cast_kernel<<<NB, 1024, 0, stream>>>(ei, (const float4*)x, (const float4*)Wl,
                                              (const float4*)Wr, (ushort4*)xh,
                                              (ushort4*)Wlb, (ushort4*)Wrb,
                                              lrank, cnt, flags);
    colscan_scan_kernel<<<SB, 256, 0, stream>>>(cnt, row_start, flags);
    scatter_kernel<<<(N_EDGES + 255) / 256, 256, 0, stream>>>(ei, row_start, cnt, lrank, csr);
    aggregate_kernel<<<2500, 256, 0, stream>>>((const us8*)xh, row_start, csr,
                                               (us8*)aggb);
    lin_mfma_kernel<<<dim3(157, 8), 256, 0, stream>>>(x, aggb, xh, Wlb, Wrb, bl, out);
}